// Round 8
// baseline (342.834 us; speedup 1.0000x reference)
//
#include <hip/hip_runtime.h>

typedef __attribute__((ext_vector_type(4))) float f32x4;
typedef __attribute__((ext_vector_type(16))) float f32x16;
typedef __attribute__((ext_vector_type(8))) __bf16 bf16x8;
typedef __attribute__((ext_vector_type(8))) short s16x8;

__device__ __forceinline__ short f2bf(float f){
  union { __bf16 h; short s; } v; v.h = (__bf16)f; return v.s;
}
__device__ __forceinline__ float bf2f(short h){
  union { unsigned u; float f; } v; v.u = ((unsigned)(unsigned short)h) << 16; return v.f;
}
__device__ __forceinline__ bf16x8 ldb8(const short* p){ return *(const bf16x8*)p; }
__device__ __forceinline__ unsigned pk2(float a, float b){
  union { __bf16 h[2]; unsigned u; } v; v.h[0] = (__bf16)a; v.h[1] = (__bf16)b; return v.u;
}

#define LOG2E 1.4426950408889634f

// ---------------- K0: groupnorm stats + weight prep (fused) ----------------
__global__ __launch_bounds__(256) void gn_stats_w(
    const float* __restrict__ x, float* __restrict__ stats,
    const float* __restrict__ qkvw, const float* __restrict__ qkvb,
    const float* __restrict__ pw, const float* __restrict__ pb,
    short* __restrict__ wq, short* __restrict__ bq,
    short* __restrict__ wp, float* __restrict__ bpo){
  if (blockIdx.x >= 256){
    const int tid = (blockIdx.x - 256)*256 + threadIdx.x;   // 0..16383
    const int nthr = 64*256;
    for (int i = tid; i < 768*256; i += nthr){
      float v = qkvw[i];
      if (i < 256*256) v *= 0.0625f;
      wq[i] = f2bf(v);
    }
    for (int i = tid; i < 256*256; i += nthr) wp[i] = f2bf(pw[i]);
    if (tid < 768){ float v = qkvb[tid]; if (tid < 256) v *= 0.0625f; bq[tid] = f2bf(v); }
    if (tid < 256) bpo[tid] = pb[tid];
    return;
  }
  const int bg = blockIdx.x;                 // 0..255 = b*32+g
  const float* p = x + (size_t)bg * 32768;   // 8 ch * 4096 contiguous
  const int t = threadIdx.x;
  float s1 = 0.f, s2 = 0.f;
  #pragma unroll
  for (int i = 0; i < 32; i++){
    f32x4 v = *(const f32x4*)(p + i*1024 + t*4);
    s1 += v[0]+v[1]+v[2]+v[3];
    s2 += v[0]*v[0]+v[1]*v[1]+v[2]*v[2]+v[3]*v[3];
  }
  #pragma unroll
  for (int off = 1; off < 64; off <<= 1){
    s1 += __shfl_xor(s1, off);
    s2 += __shfl_xor(s2, off);
  }
  __shared__ float a1[4], a2[4];
  const int w = t >> 6;
  if ((t & 63) == 0){ a1[w] = s1; a2[w] = s2; }
  __syncthreads();
  if (t == 0){
    float S1 = a1[0]+a1[1]+a1[2]+a1[3];
    float S2 = a2[0]+a2[1]+a2[2]+a2[3];
    float mu = S1 * (1.f/32768.f);
    float var = S2 * (1.f/32768.f) - mu*mu;
    stats[bg*2]   = mu;
    stats[bg*2+1] = rsqrtf(var + 1e-5f);
  }
}

// ---------------- K2: fused groupnorm-apply + qkv GEMM ---------------------
__global__ __launch_bounds__(256) void gn_qkv(
    const float* __restrict__ x, const float* __restrict__ stats,
    const float* __restrict__ nw, const float* __restrict__ nb,
    const short* __restrict__ wq, const short* __restrict__ bq,
    short* __restrict__ q_t, short* __restrict__ k_t,
    short* __restrict__ v_buf){
  const int b = blockIdx.x >> 6, nt = blockIdx.x & 63;
  const int n0 = nt << 6;
  const int t = threadIdx.x, w = t >> 6, lane = t & 63;
  const int lr = lane & 15, lg = lane >> 4;
  __shared__ short lt[64*256];   // 32 KB

  {
    const int nq = (t & 3) << 4;
    #pragma unroll
    for (int pass = 0; pass < 4; pass++){
      const int c = (t >> 2) + pass*64;
      const float mu   = stats[((b<<5) + (c>>3))*2];
      const float rstd = stats[((b<<5) + (c>>3))*2 + 1];
      const float A = rstd * nw[c];
      const float Bc = nb[c] - mu*A;
      const float* px = x + (((size_t)(b<<8) + c) << 12) + n0 + nq;
      #pragma unroll
      for (int j4 = 0; j4 < 4; j4++){
        f32x4 v = *(const f32x4*)(px + j4*4);
        #pragma unroll
        for (int e = 0; e < 4; e++){
          const int n = nq + j4*4 + e;
          lt[n*256 + (c ^ ((n&7)<<3))] = f2bf(v[e]*A + Bc);
        }
      }
    }
  }
  __syncthreads();

  for (int ch = 0; ch < 3; ch++){
    const int co0 = w*64 + ch*256;
    f32x4 acc[4][4];
    #pragma unroll
    for (int ct = 0; ct < 4; ct++)
      #pragma unroll
      for (int tt = 0; tt < 4; tt++) acc[ct][tt] = (f32x4){0.f,0.f,0.f,0.f};
    #pragma unroll
    for (int kk = 0; kk < 8; kk++){
      bf16x8 hf[4];
      #pragma unroll
      for (int tt = 0; tt < 4; tt++){
        const int n = tt*16 + lr;
        hf[tt] = ldb8(&lt[n*256 + ((kk*32 + lg*8) ^ ((n&7)<<3))]);
      }
      #pragma unroll
      for (int ct = 0; ct < 4; ct++){
        bf16x8 wf = ldb8(wq + ((size_t)(co0 + ct*16 + lr) << 8) + kk*32 + lg*8);
        if (ch < 2){
          #pragma unroll
          for (int tt = 0; tt < 4; tt++)
            acc[ct][tt] = __builtin_amdgcn_mfma_f32_16x16x32_bf16(hf[tt], wf, acc[ct][tt], 0, 0, 0);
        } else {
          #pragma unroll
          for (int tt = 0; tt < 4; tt++)
            acc[ct][tt] = __builtin_amdgcn_mfma_f32_16x16x32_bf16(wf, hf[tt], acc[ct][tt], 0, 0, 0);
        }
      }
    }
    if (ch < 2){
      short* dst = (ch == 0) ? q_t : k_t;
      const int cb = co0 - ch*256;
      #pragma unroll
      for (int ct = 0; ct < 4; ct++){
        const float bias = bf2f(bq[co0 + ct*16 + lr]);
        #pragma unroll
        for (int tt = 0; tt < 4; tt++){
          #pragma unroll
          for (int i = 0; i < 4; i++){
            const int row = n0 + tt*16 + lg*4 + i;
            dst[(((size_t)b*4096 + row) << 8) + cb + ct*16 + lr] = f2bf(acc[ct][tt][i] + bias);
          }
        }
      }
    } else {
      #pragma unroll
      for (int ct = 0; ct < 4; ct++){
        #pragma unroll
        for (int i = 0; i < 4; i++){
          const int co = co0 + ct*16 + lg*4 + i;
          const float bias = bf2f(bq[co]);
          #pragma unroll
          for (int tt = 0; tt < 4; tt++){
            v_buf[(((size_t)(b*256 + co - 512)) << 12) + n0 + tt*16 + lr] = f2bf(acc[ct][tt][i] + bias);
          }
        }
      }
    }
  }
}

// ======================= flash attention ===================================
// 4 waves x 32 q (QB=128), KB=32, 32x32x16 MFMA, swapped QK^T softmax
// (round-6 proven body: shfl_xor exchange) + dual-chain sf accumulation.
template<int NKH>
__global__ __launch_bounds__(256, 2) void attn_flash_t(
    const short* __restrict__ q_t, const short* __restrict__ k_t,
    const short* __restrict__ v_b, short* __restrict__ o0,
    short* __restrict__ o1, float* __restrict__ ml){
  constexpr int NT = 128 / NKH;
  const int b = blockIdx.x & 7;
  const int rest = blockIdx.x >> 3;
  const int kh = rest & (NKH - 1);
  const int qt = rest / NKH;
  const char* kbase = (const char*)(k_t + (((size_t)b*4096 + kh*NT*32) << 8));
  const char* vbase = (const char*)(v_b + (((size_t)b*256) << 12) + (size_t)kh*NT*32);

  const int t = threadIdx.x, w = t >> 6, l = t & 63;
  const int lq = l & 31, hi = l >> 5;
  const int q0 = qt*128 + w*32;

  __shared__ short smem[32768];   // 64 KB: [buf2][K 16KB | V 16KB]
  char* lds = (char*)smem;

  bf16x8 qf[16];
  {
    const short* pq = q_t + (((size_t)b*4096 + q0 + lq) << 8) + hi*8;
    #pragma unroll
    for (int ks = 0; ks < 16; ks++) qf[ks] = ldb8(pq + ks*16);
  }
  f32x16 of[8];
  #pragma unroll
  for (int ct = 0; ct < 8; ct++)
    #pragma unroll
    for (int r = 0; r < 16; r++) of[ct][r] = 0.f;
  float m_run = -1.0e30f, l_run = 0.f;

  const char* ksrc[4]; const char* vsrc[4];
  #pragma unroll
  for (int j = 0; j < 4; j++){
    const int key = w*8 + j*2 + hi;
    ksrc[j] = kbase + key*512 + (((l&31)*16) ^ ((key&15)<<4));
    const int c = w*64 + j*16 + (l>>2);
    vsrc[j] = vbase + (size_t)c*8192 + (((l&3)*16) ^ (((c>>1)&3)<<4));
  }

  #define STAGE(buf, kt_) do {                                               \
    _Pragma("unroll")                                                        \
    for (int j = 0; j < 4; j++)                                              \
      __builtin_amdgcn_global_load_lds(                                      \
        (const __attribute__((address_space(1))) unsigned*)(ksrc[j] + (size_t)(kt_)*16384), \
        (__attribute__((address_space(3))) unsigned*)(lds + (buf)*32768 + w*4096 + j*1024), \
        16, 0, 0);                                                           \
    _Pragma("unroll")                                                        \
    for (int j = 0; j < 4; j++)                                              \
      __builtin_amdgcn_global_load_lds(                                      \
        (const __attribute__((address_space(1))) unsigned*)(vsrc[j] + (size_t)(kt_)*64),    \
        (__attribute__((address_space(3))) unsigned*)(lds + (buf)*32768 + 16384 + w*4096 + j*1024), \
        16, 0, 0);                                                           \
  } while (0)

  STAGE(0, 0);
  __syncthreads();

  const int hi16 = hi*16;
  const int swzKr = (lq & 15) << 4;
  const int swzV  = ((lq >> 1) & 3) << 4;
  int cur = 0;

  for (int kt2 = 0; kt2 < NT; kt2++){
    if (kt2 + 1 < NT) STAGE(cur^1, kt2+1);
    const char* Kb = lds + cur*32768;
    const char* Vb = lds + cur*32768 + 16384;

    // ---- S^T = mfma(K, Q): two independent 8-deep chains ----
    f32x16 sfa, sfb;
    #pragma unroll
    for (int r = 0; r < 16; r++){ sfa[r] = 0.f; sfb[r] = 0.f; }
    #pragma unroll
    for (int ks = 0; ks < 8; ks++){
      bf16x8 kfa = ldb8((const short*)(Kb + (lq<<9) + ((ks*32 + hi16) ^ swzKr)));
      bf16x8 kfb = ldb8((const short*)(Kb + (lq<<9) + (((ks+8)*32 + hi16) ^ swzKr)));
      sfa = __builtin_amdgcn_mfma_f32_32x32x16_bf16(kfa, qf[ks], sfa, 0, 0, 0);
      sfb = __builtin_amdgcn_mfma_f32_32x32x16_bf16(kfb, qf[ks+8], sfb, 0, 0, 0);
    }
    f32x16 sf;
    #pragma unroll
    for (int r = 0; r < 16; r++) sf[r] = sfa[r] + sfb[r];

    // ---- online softmax, in-register (lane pair l <-> l^32) ----
    float pm = sf[0];
    #pragma unroll
    for (int r = 1; r < 16; r++) pm = fmaxf(pm, sf[r]);
    pm = fmaxf(pm, __shfl_xor(pm, 32));
    if (!__all(pm <= m_run + 8.f)){          // defer-max (THR=8)
      const float mn = fmaxf(m_run, pm);
      const float corr = exp2f((m_run - mn) * LOG2E);
      #pragma unroll
      for (int ct = 0; ct < 8; ct++)
        #pragma unroll
        for (int r = 0; r < 16; r++) of[ct][r] *= corr;
      l_run *= corr;
      m_run = mn;
    }
    const float mL = m_run * LOG2E;
    float p[16]; float s = 0.f;
    #pragma unroll
    for (int r = 0; r < 16; r++){
      p[r] = exp2f(__builtin_fmaf(sf[r], LOG2E, -mL));
      s += p[r];
    }
    l_run += s + __shfl_xor(s, 32);

    // ---- pack P -> bf16 A-frags (exchange halves with lane^32) ----
    unsigned own[8];
    #pragma unroll
    for (int ks = 0; ks < 2; ks++){
      own[ks*4+0] = pk2(p[ks*8+0], p[ks*8+1]);
      own[ks*4+1] = pk2(p[ks*8+2], p[ks*8+3]);
      own[ks*4+2] = pk2(p[ks*8+4], p[ks*8+5]);
      own[ks*4+3] = pk2(p[ks*8+6], p[ks*8+7]);
    }
    unsigned prt[8];
    #pragma unroll
    for (int i = 0; i < 8; i++) prt[i] = __shfl_xor(own[i], 32);
    bf16x8 pfrag[2];
    #pragma unroll
    for (int ks = 0; ks < 2; ks++){
      union { unsigned u[4]; bf16x8 v; } uu;
      uu.u[0] = hi ? prt[ks*4+2] : own[ks*4+0];
      uu.u[1] = hi ? prt[ks*4+3] : own[ks*4+1];
      uu.u[2] = hi ? own[ks*4+2] : prt[ks*4+0];
      uu.u[3] = hi ? own[ks*4+3] : prt[ks*4+1];
      pfrag[ks] = uu.v;
    }

    // ---- PV ----
    #pragma unroll
    for (int ks = 0; ks < 2; ks++){
      #pragma unroll
      for (int ct = 0; ct < 8; ct++){
        bf16x8 vf = ldb8((const short*)(Vb + ((ct*32 + lq)<<6) + ((ks*32 + hi16) ^ swzV)));
        of[ct] = __builtin_amdgcn_mfma_f32_32x32x16_bf16(pfrag[ks], vf, of[ct], 0, 0, 0);
      }
    }
    __syncthreads();
    cur ^= 1;
  }
  #undef STAGE

  short* ohp;
  if constexpr (NKH == 1) ohp = o0; else ohp = kh ? o1 : o0;
  short* po = ohp + (((size_t)b*4096 + q0) << 8);
  #pragma unroll
  for (int r = 0; r < 16; r++){
    const int row = (r&3) + 8*(r>>2) + 4*hi;
    const float lv = __shfl(l_run, row);
    const float inv = __builtin_amdgcn_rcpf(lv);
    #pragma unroll
    for (int ct = 0; ct < 8; ct++){
      po[(size_t)row*256 + ct*32 + lq] = f2bf(of[ct][r] * inv);
    }
  }
  if constexpr (NKH > 1){
    if (l < 32){
      const size_t mi = (((size_t)(kh*8 + b))*4096 + q0 + l)*2;
      ml[mi]   = m_run;
      ml[mi+1] = l_run;
    }
  }
}

// ---------------- K5: proj GEMM + bias + residual (+ fused split-merge) ----
template<int MERGE>
__global__ __launch_bounds__(256) void proj_res(
    const short* __restrict__ o0, const short* __restrict__ o1,
    const float* __restrict__ ml, const short* __restrict__ wp,
    const float* __restrict__ bp, const float* __restrict__ x,
    float* __restrict__ out){
  const int b = blockIdx.x >> 6, qt = blockIdx.x & 63;
  const int q0 = qt << 6;
  const int t = threadIdx.x, w = t >> 6, lane = t & 63;
  const int lr = lane & 15, lg = lane >> 4;

  float a0[4], a1[4];
  if constexpr (MERGE){
    #pragma unroll
    for (int tt = 0; tt < 4; tt++){
      const int q = q0 + tt*16 + lr;
      const size_t m0i = (((size_t)b)*4096 + q)*2;
      const size_t m1i = (((size_t)(8 + b))*4096 + q)*2;
      const float m0 = ml[m0i], l0 = ml[m0i+1];
      const float m1 = ml[m1i], l1 = ml[m1i+1];
      const float M  = fmaxf(m0, m1);
      const float w0 = l0 * exp2f((m0 - M) * LOG2E);
      const float w1 = l1 * exp2f((m1 - M) * LOG2E);
      const float inv = 1.f / (w0 + w1);
      a0[tt] = w0 * inv; a1[tt] = w1 * inv;
    }
  }

  f32x4 acc[4][4];
  #pragma unroll
  for (int cg = 0; cg < 4; cg++)
    #pragma unroll
    for (int tt = 0; tt < 4; tt++) acc[cg][tt] = (f32x4){0.f,0.f,0.f,0.f};

  #pragma unroll
  for (int kk = 0; kk < 8; kk++){
    bf16x8 bfr[4];
    #pragma unroll
    for (int tt = 0; tt < 4; tt++){
      const size_t off = (((size_t)b*4096 + q0 + tt*16 + lr) << 8) + kk*32 + lg*8;
      if constexpr (MERGE){
        s16x8 v0 = *(const s16x8*)(o0 + off);
        s16x8 v1 = *(const s16x8*)(o1 + off);
        union { __bf16 h[8]; bf16x8 v; } r;
        #pragma unroll
        for (int e = 0; e < 8; e++)
          r.h[e] = (__bf16)(a0[tt]*bf2f(v0[e]) + a1[tt]*bf2f(v1[e]));
        bfr[tt] = r.v;
      } else {
        bfr[tt] = ldb8(o0 + off);
      }
    }
    #pragma unroll
    for (int cg = 0; cg < 4; cg++){
      bf16x8 af = ldb8(wp + (((size_t)(cg*64 + w*16 + lr)) << 8) + kk*32 + lg*8);
      #pragma unroll
      for (int tt = 0; tt < 4; tt++)
        acc[cg][tt] = __builtin_amdgcn_mfma_f32_16x16x32_bf16(af, bfr[tt], acc[cg][tt], 0, 0, 0);
    }
  }
  #pragma unroll
  for (int cg = 0; cg < 4; cg++){
    #pragma unroll
    for (int i = 0; i < 4; i++){
      const int co = cg*64 + w*16 + lg*4 + i;
      const float bias = bp[co];
      #pragma unroll
      for (int tt = 0; tt < 4; tt++){
        const int q = q0 + tt*16 + lr;
        const size_t idx = (((size_t)(b*256 + co)) << 12) + q;
        out[idx] = acc[cg][tt][i] + bias + x[idx];
      }
    }
  }
}

// ---------------- workspace layout -----------------------------------------
static constexpr size_t SZT  = (size_t)8 * 4096 * 256 * 2;  // 16 MB bf16 tensor
static constexpr size_t OFF_STATS = 0;                      // 2 KB
static constexpr size_t OFF_WQ = 4096;
static constexpr size_t OFF_BQ = OFF_WQ + 768*256*2;
static constexpr size_t OFF_WP = OFF_BQ + 768*2;
static constexpr size_t OFF_BP = OFF_WP + 256*256*2;
static constexpr size_t OFF_HT = 532480;                    // oh0
static constexpr size_t OFF_QT = OFF_HT + SZT;
static constexpr size_t OFF_KT = OFF_QT + SZT;
static constexpr size_t OFF_V  = OFF_KT + SZT;
static constexpr size_t OFF_OT = OFF_V + SZT;
static constexpr size_t OFF_OH1 = OFF_OT + SZT;
static constexpr size_t OFF_ML  = OFF_OH1 + SZT;
static constexpr size_t WS_NEED_SPLIT = OFF_ML + (size_t)2*8*4096*2*4;

extern "C" void kernel_launch(void* const* d_in, const int* in_sizes, int n_in,
                              void* d_out, int out_size, void* d_ws, size_t ws_size,
                              hipStream_t stream){
  const float* x    = (const float*)d_in[0];
  const float* nw   = (const float*)d_in[1];
  const float* nb   = (const float*)d_in[2];
  const float* qkvw = (const float*)d_in[3];
  const float* qkvb = (const float*)d_in[4];
  const float* pw   = (const float*)d_in[5];
  const float* pb   = (const float*)d_in[6];
  float* out = (float*)d_out;
  char* ws = (char*)d_ws;

  float* stats = (float*)(ws + OFF_STATS);
  short* wq    = (short*)(ws + OFF_WQ);
  short* bq    = (short*)(ws + OFF_BQ);
  short* wp    = (short*)(ws + OFF_WP);
  float* bp    = (float*)(ws + OFF_BP);
  short* oh0   = (short*)(ws + OFF_HT);
  short* qt    = (short*)(ws + OFF_QT);
  short* kt    = (short*)(ws + OFF_KT);
  short* vb    = (short*)(ws + OFF_V);
  short* ot    = (short*)(ws + OFF_OT);
  short* oh1   = (short*)(ws + OFF_OH1);
  float* ml    = (float*)(ws + OFF_ML);

  gn_stats_w<<<320, 256, 0, stream>>>(x, stats, qkvw, qkvb, pw, pb, wq, bq, wp, bp);
  gn_qkv    <<<512, 256, 0, stream>>>(x, stats, nw, nb, wq, bq, qt, kt, vb);
  if (ws_size >= WS_NEED_SPLIT){
    attn_flash_t<2><<<512, 256, 0, stream>>>(qt, kt, vb, oh0, oh1, ml);
    proj_res<1>    <<<512, 256, 0, stream>>>(oh0, oh1, ml, wp, bp, x, out);
  } else {
    attn_flash_t<1><<<256, 256, 0, stream>>>(qt, kt, vb, ot, ot, ml);
    proj_res<0>    <<<512, 256, 0, stream>>>(ot, ot, ml, wp, bp, x, out);
  }
}

// Round 9
// 312.808 us; speedup vs baseline: 1.0960x; 1.0960x over previous
//
#include <hip/hip_runtime.h>

typedef __attribute__((ext_vector_type(4))) float f32x4;
typedef __attribute__((ext_vector_type(16))) float f32x16;
typedef __attribute__((ext_vector_type(8))) __bf16 bf16x8;
typedef __attribute__((ext_vector_type(8))) short s16x8;

__device__ __forceinline__ short f2bf(float f){
  union { __bf16 h; short s; } v; v.h = (__bf16)f; return v.s;
}
__device__ __forceinline__ float bf2f(short h){
  union { unsigned u; float f; } v; v.u = ((unsigned)(unsigned short)h) << 16; return v.f;
}
__device__ __forceinline__ bf16x8 ldb8(const short* p){ return *(const bf16x8*)p; }
__device__ __forceinline__ unsigned pk2(float a, float b){
  union { __bf16 h[2]; unsigned u; } v; v.h[0] = (__bf16)a; v.h[1] = (__bf16)b; return v.u;
}

#define LOG2E 1.4426950408889634f

// ---------------- K0: groupnorm stats + weight prep (fused) ----------------
__global__ __launch_bounds__(256) void gn_stats_w(
    const float* __restrict__ x, float* __restrict__ stats,
    const float* __restrict__ qkvw, const float* __restrict__ qkvb,
    const float* __restrict__ pw, const float* __restrict__ pb,
    short* __restrict__ wq, short* __restrict__ bq,
    short* __restrict__ wp, float* __restrict__ bpo){
  if (blockIdx.x >= 256){
    const int tid = (blockIdx.x - 256)*256 + threadIdx.x;   // 0..16383
    const int nthr = 64*256;
    for (int i = tid; i < 768*256; i += nthr){
      float v = qkvw[i];
      if (i < 256*256) v *= 0.0625f;
      wq[i] = f2bf(v);
    }
    for (int i = tid; i < 256*256; i += nthr) wp[i] = f2bf(pw[i]);
    if (tid < 768){ float v = qkvb[tid]; if (tid < 256) v *= 0.0625f; bq[tid] = f2bf(v); }
    if (tid < 256) bpo[tid] = pb[tid];
    return;
  }
  const int bg = blockIdx.x;                 // 0..255 = b*32+g
  const float* p = x + (size_t)bg * 32768;   // 8 ch * 4096 contiguous
  const int t = threadIdx.x;
  float s1 = 0.f, s2 = 0.f;
  #pragma unroll
  for (int i = 0; i < 32; i++){
    f32x4 v = *(const f32x4*)(p + i*1024 + t*4);
    s1 += v[0]+v[1]+v[2]+v[3];
    s2 += v[0]*v[0]+v[1]*v[1]+v[2]*v[2]+v[3]*v[3];
  }
  #pragma unroll
  for (int off = 1; off < 64; off <<= 1){
    s1 += __shfl_xor(s1, off);
    s2 += __shfl_xor(s2, off);
  }
  __shared__ float a1[4], a2[4];
  const int w = t >> 6;
  if ((t & 63) == 0){ a1[w] = s1; a2[w] = s2; }
  __syncthreads();
  if (t == 0){
    float S1 = a1[0]+a1[1]+a1[2]+a1[3];
    float S2 = a2[0]+a2[1]+a2[2]+a2[3];
    float mu = S1 * (1.f/32768.f);
    float var = S2 * (1.f/32768.f) - mu*mu;
    stats[bg*2]   = mu;
    stats[bg*2+1] = rsqrtf(var + 1e-5f);
  }
}

// ---------------- K2: fused groupnorm-apply + qkv GEMM ---------------------
__global__ __launch_bounds__(256) void gn_qkv(
    const float* __restrict__ x, const float* __restrict__ stats,
    const float* __restrict__ nw, const float* __restrict__ nb,
    const short* __restrict__ wq, const short* __restrict__ bq,
    short* __restrict__ q_t, short* __restrict__ k_t,
    short* __restrict__ v_buf){
  const int b = blockIdx.x >> 6, nt = blockIdx.x & 63;
  const int n0 = nt << 6;
  const int t = threadIdx.x, w = t >> 6, lane = t & 63;
  const int lr = lane & 15, lg = lane >> 4;
  __shared__ short lt[64*256];   // 32 KB

  {
    const int nq = (t & 3) << 4;
    #pragma unroll
    for (int pass = 0; pass < 4; pass++){
      const int c = (t >> 2) + pass*64;
      const float mu   = stats[((b<<5) + (c>>3))*2];
      const float rstd = stats[((b<<5) + (c>>3))*2 + 1];
      const float A = rstd * nw[c];
      const float Bc = nb[c] - mu*A;
      const float* px = x + (((size_t)(b<<8) + c) << 12) + n0 + nq;
      #pragma unroll
      for (int j4 = 0; j4 < 4; j4++){
        f32x4 v = *(const f32x4*)(px + j4*4);
        #pragma unroll
        for (int e = 0; e < 4; e++){
          const int n = nq + j4*4 + e;
          lt[n*256 + (c ^ ((n&7)<<3))] = f2bf(v[e]*A + Bc);
        }
      }
    }
  }
  __syncthreads();

  for (int ch = 0; ch < 3; ch++){
    const int co0 = w*64 + ch*256;
    f32x4 acc[4][4];
    #pragma unroll
    for (int ct = 0; ct < 4; ct++)
      #pragma unroll
      for (int tt = 0; tt < 4; tt++) acc[ct][tt] = (f32x4){0.f,0.f,0.f,0.f};
    #pragma unroll
    for (int kk = 0; kk < 8; kk++){
      bf16x8 hf[4];
      #pragma unroll
      for (int tt = 0; tt < 4; tt++){
        const int n = tt*16 + lr;
        hf[tt] = ldb8(&lt[n*256 + ((kk*32 + lg*8) ^ ((n&7)<<3))]);
      }
      #pragma unroll
      for (int ct = 0; ct < 4; ct++){
        bf16x8 wf = ldb8(wq + ((size_t)(co0 + ct*16 + lr) << 8) + kk*32 + lg*8);
        if (ch < 2){
          #pragma unroll
          for (int tt = 0; tt < 4; tt++)
            acc[ct][tt] = __builtin_amdgcn_mfma_f32_16x16x32_bf16(hf[tt], wf, acc[ct][tt], 0, 0, 0);
        } else {
          #pragma unroll
          for (int tt = 0; tt < 4; tt++)
            acc[ct][tt] = __builtin_amdgcn_mfma_f32_16x16x32_bf16(wf, hf[tt], acc[ct][tt], 0, 0, 0);
        }
      }
    }
    if (ch < 2){
      short* dst = (ch == 0) ? q_t : k_t;
      const int cb = co0 - ch*256;
      #pragma unroll
      for (int ct = 0; ct < 4; ct++){
        const float bias = bf2f(bq[co0 + ct*16 + lr]);
        #pragma unroll
        for (int tt = 0; tt < 4; tt++){
          #pragma unroll
          for (int i = 0; i < 4; i++){
            const int row = n0 + tt*16 + lg*4 + i;
            dst[(((size_t)b*4096 + row) << 8) + cb + ct*16 + lr] = f2bf(acc[ct][tt][i] + bias);
          }
        }
      }
    } else {
      #pragma unroll
      for (int ct = 0; ct < 4; ct++){
        #pragma unroll
        for (int i = 0; i < 4; i++){
          const int co = co0 + ct*16 + lg*4 + i;
          const float bias = bf2f(bq[co]);
          #pragma unroll
          for (int tt = 0; tt < 4; tt++){
            v_buf[(((size_t)(b*256 + co - 512)) << 12) + n0 + tt*16 + lr] = f2bf(acc[ct][tt][i] + bias);
          }
        }
      }
    }
  }
}

// ======================= flash attention ===================================
// Round-6 proven body: 4 waves x 32 q (QB=128), KB=32, 32x32x16 MFMA,
// swapped QK^T in-register softmax (single sf chain), shfl_xor P-exchange,
// global_load_lds dbuf staging, 1 barrier per k-tile.
template<int NKH>
__global__ __launch_bounds__(256, 2) void attn_flash_t(
    const short* __restrict__ q_t, const short* __restrict__ k_t,
    const short* __restrict__ v_b, short* __restrict__ o0,
    short* __restrict__ o1, float* __restrict__ ml){
  constexpr int NT = 128 / NKH;
  const int b = blockIdx.x & 7;
  const int rest = blockIdx.x >> 3;
  const int kh = rest & (NKH - 1);
  const int qt = rest / NKH;
  const char* kbase = (const char*)(k_t + (((size_t)b*4096 + kh*NT*32) << 8));
  const char* vbase = (const char*)(v_b + (((size_t)b*256) << 12) + (size_t)kh*NT*32);

  const int t = threadIdx.x, w = t >> 6, l = t & 63;
  const int lq = l & 31, hi = l >> 5;
  const int q0 = qt*128 + w*32;

  __shared__ short smem[32768];   // 64 KB: [buf2][K 16KB | V 16KB]
  char* lds = (char*)smem;

  bf16x8 qf[16];
  {
    const short* pq = q_t + (((size_t)b*4096 + q0 + lq) << 8) + hi*8;
    #pragma unroll
    for (int ks = 0; ks < 16; ks++) qf[ks] = ldb8(pq + ks*16);
  }
  f32x16 of[8];
  #pragma unroll
  for (int ct = 0; ct < 8; ct++)
    #pragma unroll
    for (int r = 0; r < 16; r++) of[ct][r] = 0.f;
  float m_run = -1.0e30f, l_run = 0.f;

  const char* ksrc[4]; const char* vsrc[4];
  #pragma unroll
  for (int j = 0; j < 4; j++){
    const int key = w*8 + j*2 + hi;
    ksrc[j] = kbase + key*512 + (((l&31)*16) ^ ((key&15)<<4));
    const int c = w*64 + j*16 + (l>>2);
    vsrc[j] = vbase + (size_t)c*8192 + (((l&3)*16) ^ (((c>>1)&3)<<4));
  }

  #define STAGE(buf, kt_) do {                                               \
    _Pragma("unroll")                                                        \
    for (int j = 0; j < 4; j++)                                              \
      __builtin_amdgcn_global_load_lds(                                      \
        (const __attribute__((address_space(1))) unsigned*)(ksrc[j] + (size_t)(kt_)*16384), \
        (__attribute__((address_space(3))) unsigned*)(lds + (buf)*32768 + w*4096 + j*1024), \
        16, 0, 0);                                                           \
    _Pragma("unroll")                                                        \
    for (int j = 0; j < 4; j++)                                              \
      __builtin_amdgcn_global_load_lds(                                      \
        (const __attribute__((address_space(1))) unsigned*)(vsrc[j] + (size_t)(kt_)*64),    \
        (__attribute__((address_space(3))) unsigned*)(lds + (buf)*32768 + 16384 + w*4096 + j*1024), \
        16, 0, 0);                                                           \
  } while (0)

  STAGE(0, 0);
  __syncthreads();

  const int hi16 = hi*16;
  const int swzKr = (lq & 15) << 4;
  const int swzV  = ((lq >> 1) & 3) << 4;
  int cur = 0;

  for (int kt2 = 0; kt2 < NT; kt2++){
    if (kt2 + 1 < NT) STAGE(cur^1, kt2+1);
    const char* Kb = lds + cur*32768;
    const char* Vb = lds + cur*32768 + 16384;

    // ---- S^T = mfma(K, Q) ----
    f32x16 sf;
    #pragma unroll
    for (int r = 0; r < 16; r++) sf[r] = 0.f;
    #pragma unroll
    for (int ks = 0; ks < 16; ks++){
      bf16x8 kf = ldb8((const short*)(Kb + (lq<<9) + ((ks*32 + hi16) ^ swzKr)));
      sf = __builtin_amdgcn_mfma_f32_32x32x16_bf16(kf, qf[ks], sf, 0, 0, 0);
    }

    // ---- online softmax, in-register (lane pair l <-> l^32) ----
    float pm = sf[0];
    #pragma unroll
    for (int r = 1; r < 16; r++) pm = fmaxf(pm, sf[r]);
    pm = fmaxf(pm, __shfl_xor(pm, 32));
    if (!__all(pm <= m_run + 8.f)){          // defer-max (THR=8)
      const float mn = fmaxf(m_run, pm);
      const float corr = exp2f((m_run - mn) * LOG2E);
      #pragma unroll
      for (int ct = 0; ct < 8; ct++)
        #pragma unroll
        for (int r = 0; r < 16; r++) of[ct][r] *= corr;
      l_run *= corr;
      m_run = mn;
    }
    const float mL = m_run * LOG2E;
    float p[16]; float s = 0.f;
    #pragma unroll
    for (int r = 0; r < 16; r++){
      p[r] = exp2f(__builtin_fmaf(sf[r], LOG2E, -mL));
      s += p[r];
    }
    l_run += s + __shfl_xor(s, 32);

    // ---- pack P -> bf16 A-frags (exchange halves with lane^32) ----
    unsigned own[8];
    #pragma unroll
    for (int ks = 0; ks < 2; ks++){
      own[ks*4+0] = pk2(p[ks*8+0], p[ks*8+1]);
      own[ks*4+1] = pk2(p[ks*8+2], p[ks*8+3]);
      own[ks*4+2] = pk2(p[ks*8+4], p[ks*8+5]);
      own[ks*4+3] = pk2(p[ks*8+6], p[ks*8+7]);
    }
    unsigned prt[8];
    #pragma unroll
    for (int i = 0; i < 8; i++) prt[i] = __shfl_xor(own[i], 32);
    bf16x8 pfrag[2];
    #pragma unroll
    for (int ks = 0; ks < 2; ks++){
      union { unsigned u[4]; bf16x8 v; } uu;
      uu.u[0] = hi ? prt[ks*4+2] : own[ks*4+0];
      uu.u[1] = hi ? prt[ks*4+3] : own[ks*4+1];
      uu.u[2] = hi ? own[ks*4+2] : prt[ks*4+0];
      uu.u[3] = hi ? own[ks*4+3] : prt[ks*4+1];
      pfrag[ks] = uu.v;
    }

    // ---- PV ----
    #pragma unroll
    for (int ks = 0; ks < 2; ks++){
      #pragma unroll
      for (int ct = 0; ct < 8; ct++){
        bf16x8 vf = ldb8((const short*)(Vb + ((ct*32 + lq)<<6) + ((ks*32 + hi16) ^ swzV)));
        of[ct] = __builtin_amdgcn_mfma_f32_32x32x16_bf16(pfrag[ks], vf, of[ct], 0, 0, 0);
      }
    }
    __syncthreads();
    cur ^= 1;
  }
  #undef STAGE

  short* ohp;
  if constexpr (NKH == 1) ohp = o0; else ohp = kh ? o1 : o0;
  short* po = ohp + (((size_t)b*4096 + q0) << 8);
  #pragma unroll
  for (int r = 0; r < 16; r++){
    const int row = (r&3) + 8*(r>>2) + 4*hi;
    const float lv = __shfl(l_run, row);
    const float inv = __builtin_amdgcn_rcpf(lv);
    #pragma unroll
    for (int ct = 0; ct < 8; ct++){
      po[(size_t)row*256 + ct*32 + lq] = f2bf(of[ct][r] * inv);
    }
  }
  if constexpr (NKH > 1){
    if (l < 32){
      const size_t mi = (((size_t)(kh*8 + b))*4096 + q0 + l)*2;
      ml[mi]   = m_run;
      ml[mi+1] = l_run;
    }
  }
}

// ---------------- K5: proj GEMM + bias + residual (+ fused split-merge) ----
template<int MERGE>
__global__ __launch_bounds__(256) void proj_res(
    const short* __restrict__ o0, const short* __restrict__ o1,
    const float* __restrict__ ml, const short* __restrict__ wp,
    const float* __restrict__ bp, const float* __restrict__ x,
    float* __restrict__ out){
  const int b = blockIdx.x >> 6, qt = blockIdx.x & 63;
  const int q0 = qt << 6;
  const int t = threadIdx.x, w = t >> 6, lane = t & 63;
  const int lr = lane & 15, lg = lane >> 4;

  float a0[4], a1[4];
  if constexpr (MERGE){
    #pragma unroll
    for (int tt = 0; tt < 4; tt++){
      const int q = q0 + tt*16 + lr;
      const size_t m0i = (((size_t)b)*4096 + q)*2;
      const size_t m1i = (((size_t)(8 + b))*4096 + q)*2;
      const float m0 = ml[m0i], l0 = ml[m0i+1];
      const float m1 = ml[m1i], l1 = ml[m1i+1];
      const float M  = fmaxf(m0, m1);
      const float w0 = l0 * exp2f((m0 - M) * LOG2E);
      const float w1 = l1 * exp2f((m1 - M) * LOG2E);
      const float inv = 1.f / (w0 + w1);
      a0[tt] = w0 * inv; a1[tt] = w1 * inv;
    }
  }

  f32x4 acc[4][4];
  #pragma unroll
  for (int cg = 0; cg < 4; cg++)
    #pragma unroll
    for (int tt = 0; tt < 4; tt++) acc[cg][tt] = (f32x4){0.f,0.f,0.f,0.f};

  #pragma unroll
  for (int kk = 0; kk < 8; kk++){
    bf16x8 bfr[4];
    #pragma unroll
    for (int tt = 0; tt < 4; tt++){
      const size_t off = (((size_t)b*4096 + q0 + tt*16 + lr) << 8) + kk*32 + lg*8;
      if constexpr (MERGE){
        s16x8 v0 = *(const s16x8*)(o0 + off);
        s16x8 v1 = *(const s16x8*)(o1 + off);
        union { __bf16 h[8]; bf16x8 v; } r;
        #pragma unroll
        for (int e = 0; e < 8; e++)
          r.h[e] = (__bf16)(a0[tt]*bf2f(v0[e]) + a1[tt]*bf2f(v1[e]));
        bfr[tt] = r.v;
      } else {
        bfr[tt] = ldb8(o0 + off);
      }
    }
    #pragma unroll
    for (int cg = 0; cg < 4; cg++){
      bf16x8 af = ldb8(wp + (((size_t)(cg*64 + w*16 + lr)) << 8) + kk*32 + lg*8);
      #pragma unroll
      for (int tt = 0; tt < 4; tt++)
        acc[cg][tt] = __builtin_amdgcn_mfma_f32_16x16x32_bf16(af, bfr[tt], acc[cg][tt], 0, 0, 0);
    }
  }
  #pragma unroll
  for (int cg = 0; cg < 4; cg++){
    #pragma unroll
    for (int i = 0; i < 4; i++){
      const int co = cg*64 + w*16 + lg*4 + i;
      const float bias = bp[co];
      #pragma unroll
      for (int tt = 0; tt < 4; tt++){
        const int q = q0 + tt*16 + lr;
        const size_t idx = (((size_t)(b*256 + co)) << 12) + q;
        out[idx] = acc[cg][tt][i] + bias + x[idx];
      }
    }
  }
}

// ---------------- workspace layout -----------------------------------------
static constexpr size_t SZT  = (size_t)8 * 4096 * 256 * 2;  // 16 MB bf16 tensor
static constexpr size_t OFF_STATS = 0;                      // 2 KB
static constexpr size_t OFF_WQ = 4096;
static constexpr size_t OFF_BQ = OFF_WQ + 768*256*2;
static constexpr size_t OFF_WP = OFF_BQ + 768*2;
static constexpr size_t OFF_BP = OFF_WP + 256*256*2;
static constexpr size_t OFF_HT = 532480;                    // oh0
static constexpr size_t OFF_QT = OFF_HT + SZT;
static constexpr size_t OFF_KT = OFF_QT + SZT;
static constexpr size_t OFF_V  = OFF_KT + SZT;
static constexpr size_t OFF_OT = OFF_V + SZT;
static constexpr size_t OFF_OH1 = OFF_OT + SZT;
static constexpr size_t OFF_ML  = OFF_OH1 + SZT;
static constexpr size_t WS_NEED_SPLIT = OFF_ML + (size_t)2*8*4096*2*4;

extern "C" void kernel_launch(void* const* d_in, const int* in_sizes, int n_in,
                              void* d_out, int out_size, void* d_ws, size_t ws_size,
                              hipStream_t stream){
  const float* x    = (const float*)d_in[0];
  const float* nw   = (const float*)d_in[1];
  const float* nb   = (const float*)d_in[2];
  const float* qkvw = (const float*)d_in[3];
  const float* qkvb = (const float*)d_in[4];
  const float* pw   = (const float*)d_in[5];
  const float* pb   = (const float*)d_in[6];
  float* out = (float*)d_out;
  char* ws = (char*)d_ws;

  float* stats = (float*)(ws + OFF_STATS);
  short* wq    = (short*)(ws + OFF_WQ);
  short* bq    = (short*)(ws + OFF_BQ);
  short* wp    = (short*)(ws + OFF_WP);
  float* bp    = (float*)(ws + OFF_BP);
  short* oh0   = (short*)(ws + OFF_HT);
  short* qt    = (short*)(ws + OFF_QT);
  short* kt    = (short*)(ws + OFF_KT);
  short* vb    = (short*)(ws + OFF_V);
  short* ot    = (short*)(ws + OFF_OT);
  short* oh1   = (short*)(ws + OFF_OH1);
  float* ml    = (float*)(ws + OFF_ML);

  gn_stats_w<<<320, 256, 0, stream>>>(x, stats, qkvw, qkvb, pw, pb, wq, bq, wp, bp);
  gn_qkv    <<<512, 256, 0, stream>>>(x, stats, nw, nb, wq, bq, qt, kt, vb);
  if (ws_size >= WS_NEED_SPLIT){
    attn_flash_t<2><<<512, 256, 0, stream>>>(qt, kt, vb, oh0, oh1, ml);
    proj_res<1>    <<<512, 256, 0, stream>>>(oh0, oh1, ml, wp, bp, x, out);
  } else {
    attn_flash_t<1><<<256, 256, 0, stream>>>(qt, kt, vb, ot, ot, ml);
    proj_res<0>    <<<512, 256, 0, stream>>>(ot, ot, ml, wp, bp, x, out);
  }
}